// Round 5
// baseline (83406.940 us; speedup 1.0000x reference)
//
#include <hip/hip_runtime.h>
#include <stdint.h>

// ---------------- constants ----------------
#define T_STEPS 1000
#define BATCHN  4096
#define SDIM    128
#define ADIM    32
#define HID     256
#define TDIM    16
#define CONC    (ADIM + TDIM + SDIM)   // 176

// ---------------- threefry2x32 (exact JAX semantics) ----------------
__device__ __forceinline__ uint32_t rotl32(uint32_t v, int d) {
  return (v << d) | (v >> (32 - d));
}

__device__ __forceinline__ void threefry2x32(uint32_t k0, uint32_t k1,
                                             uint32_t x0, uint32_t x1,
                                             uint32_t& o0, uint32_t& o1) {
  uint32_t ks0 = k0, ks1 = k1, ks2 = k0 ^ k1 ^ 0x1BD11BDAu;
  x0 += ks0; x1 += ks1;
#define TF_ROUND(r) { x0 += x1; x1 = rotl32(x1, (r)); x1 ^= x0; }
  TF_ROUND(13) TF_ROUND(15) TF_ROUND(26) TF_ROUND(6)
  x0 += ks1; x1 += ks2 + 1u;
  TF_ROUND(17) TF_ROUND(29) TF_ROUND(16) TF_ROUND(24)
  x0 += ks2; x1 += ks0 + 2u;
  TF_ROUND(13) TF_ROUND(15) TF_ROUND(26) TF_ROUND(6)
  x0 += ks0; x1 += ks1 + 3u;
  TF_ROUND(17) TF_ROUND(29) TF_ROUND(16) TF_ROUND(24)
  x0 += ks1; x1 += ks2 + 4u;
  TF_ROUND(13) TF_ROUND(15) TF_ROUND(26) TF_ROUND(6)
  x0 += ks2; x1 += ks0 + 5u;
#undef TF_ROUND
  o0 = x0; o1 = x1;
}

// JAX partitionable threefry random_bits (bit_width=32): XOR combine of both words.
__device__ __forceinline__ uint32_t random_bits32_partitionable(uint32_t k0, uint32_t k1,
                                                               uint32_t j) {
  uint32_t o0, o1;
  threefry2x32(k0, k1, 0u, j, o0, o1);
  return o0 ^ o1;
}

// ---------------- XLA ErfInv (f32 Giles polynomial) ----------------
__device__ __forceinline__ float erfinv_f32(float x) {
  float w = -log1pf(-(x * x));
  float p;
  if (w < 5.0f) {
    w = w - 2.5f;
    p = 2.81022636e-08f;
    p = fmaf(p, w, 3.43273939e-07f);
    p = fmaf(p, w, -3.5233877e-06f);
    p = fmaf(p, w, -4.39150654e-06f);
    p = fmaf(p, w, 0.00021858087f);
    p = fmaf(p, w, -0.00125372503f);
    p = fmaf(p, w, -0.00417768164f);
    p = fmaf(p, w, 0.246640727f);
    p = fmaf(p, w, 1.50140941f);
  } else {
    w = sqrtf(w) - 3.0f;
    p = -0.000200214257f;
    p = fmaf(p, w, 0.000100950558f);
    p = fmaf(p, w, 0.00134934322f);
    p = fmaf(p, w, -0.00367342844f);
    p = fmaf(p, w, 0.00573950773f);
    p = fmaf(p, w, -0.0076224613f);
    p = fmaf(p, w, 0.00943887047f);
    p = fmaf(p, w, 1.00167406f);
    p = fmaf(p, w, 2.83297682f);
  }
  return p * x;
}

// bits -> N(0,1) exactly as jax.random.normal (threefry path)
__device__ __forceinline__ float bits_to_normal(uint32_t bits) {
  float f = __uint_as_float((bits >> 9) | 0x3F800000u) - 1.0f;   // [0,1)
  float u = f * 2.0f + (-0.99999994f);
  u = fmaxf(-0.99999994f, u);
  return 1.41421356237309515f * erfinv_f32(u);   // sqrt(2) as f32
}

// mish(x) = x * tanh(softplus(x)) = x * t/(t+2), t = e^x (e^x + 2)   [tanh(ln y) identity]
// clamp exp arg at 20: for x>=20, t/(t+2) == 1.0f exactly in f32.
__device__ __forceinline__ float mish_f(float x) {
  float e = expf(fminf(x, 20.0f));
  float t = fmaf(e, e, 2.0f * e);
  return x * (t / (t + 2.0f));
}

// ---------------- precompute: tf_all[1000][16], coefs[5][1000], keys[1000][2] --------
__global__ __launch_bounds__(64)
void precompute_kernel(const float* __restrict__ w_t1, const float* __restrict__ b_t1,
                       const float* __restrict__ w_t2, const float* __restrict__ b_t2,
                       float* __restrict__ tf_all, float* __restrict__ coefs,
                       uint32_t* __restrict__ keys) {
  const int i = blockIdx.x;
  const int j = threadIdx.x;
  const float tv = (float)i;
  __shared__ float hid[32];
  const float CF = (float)(-1.3157629102823120);  // -log(10000)/7
  if (j < 32) {
    float acc = b_t1[j];
#pragma unroll
    for (int k = 0; k < 16; ++k) {
      int kf = (k < 8) ? k : (k - 8);
      float fr = expf((float)kf * CF);
      float ang = tv * fr;
      float te = (k < 8) ? sinf(ang) : cosf(ang);
      acc = fmaf(te, w_t1[k * 32 + j], acc);
    }
    hid[j] = mish_f(acc);
  }
  __syncthreads();
  if (j < 16) {
    float acc = b_t2[j];
#pragma unroll
    for (int k2 = 0; k2 < 32; ++k2) acc = fmaf(hid[k2], w_t2[k2 * 16 + j], acc);
    tf_all[i * TDIM + j] = acc;
  }
  if (j == 0) {
    double t = (double)(i + 1);
    double ac  = exp(-0.1 * t / 1000.0 - 4.95 * t * t / 1.0e6);
    double acp = (i == 0) ? 1.0
        : exp(-0.1 * (t - 1.0) / 1000.0 - 4.95 * (t - 1.0) * (t - 1.0) / 1.0e6);
    double alpha = exp(-0.1 / 1000.0 - 4.95 * (2.0 * t - 1.0) / 1.0e6);
    double beta = 1.0 - alpha;
    double sr   = sqrt(1.0 / ac);
    double srm1 = sqrt(1.0 / ac - 1.0);
    double c1 = beta * sqrt(acp) / (1.0 - ac);
    double c2 = (1.0 - acp) * sqrt(alpha) / (1.0 - ac);
    double pv = beta * (1.0 - acp) / (1.0 - ac);
    double lv = log(fmax(pv, 1.0e-20));
    coefs[0 * T_STEPS + i] = (float)sr;
    coefs[1 * T_STEPS + i] = (float)srm1;
    coefs[2 * T_STEPS + i] = (float)c1;
    coefs[3 * T_STEPS + i] = (float)c2;
    float lvf = (float)lv;
    coefs[4 * T_STEPS + i] = expf(0.5f * lvf);
    uint32_t o0, o1;
    threefry2x32(0u, 1u, 0u, (uint32_t)i, o0, o1);
    keys[2 * i]     = o0;
    keys[2 * i + 1] = o1;
  }
}

// ------- dense layer, 512 threads: thread = (row r = tid>>5, chunk c = (tid&31)*4) ----
// neurons c..c+3 and c+128..c+131 (conflict-free contiguous b128 LDS writes)
template <int K>
__device__ __forceinline__ void dense48(const float* __restrict__ W,
                                        const float* __restrict__ bias,
                                        const float* __restrict__ src, int sstride,
                                        float* __restrict__ dst,
                                        int r, int c) {
  float acc0[4], acc1[4];
#pragma unroll
  for (int j = 0; j < 4; ++j) { acc0[j] = 0.0f; acc1[j] = 0.0f; }
  const float* s0 = src + r * sstride;
  const float* wp = W + c;
#pragma unroll 2
  for (int k = 0; k < K; k += 4) {
    float4 a = *reinterpret_cast<const float4*>(s0 + k);
    float wA[4][4], wB[4][4];
#pragma unroll
    for (int i = 0; i < 4; ++i) {
      *reinterpret_cast<float4*>(&wA[i][0]) = *reinterpret_cast<const float4*>(wp + i * HID);
      *reinterpret_cast<float4*>(&wB[i][0]) = *reinterpret_cast<const float4*>(wp + i * HID + 128);
    }
    float av[4] = {a.x, a.y, a.z, a.w};
#pragma unroll
    for (int i = 0; i < 4; ++i) {
#pragma unroll
      for (int j = 0; j < 4; ++j) {
        acc0[j] = fmaf(av[i], wA[i][j], acc0[j]);
        acc1[j] = fmaf(av[i], wB[i][j], acc1[j]);
      }
    }
    wp += 4 * HID;
  }
  float o0[4], o1[4];
#pragma unroll
  for (int j = 0; j < 4; ++j) {
    o0[j] = mish_f(acc0[j] + bias[c + j]);
    o1[j] = mish_f(acc1[j] + bias[c + 128 + j]);
  }
  float* d0 = dst + r * HID + c;
  *reinterpret_cast<float4*>(d0)       = *reinterpret_cast<const float4*>(&o0[0]);
  *reinterpret_cast<float4*>(d0 + 128) = *reinterpret_cast<const float4*>(&o1[0]);
}

// ---------------- persistent main kernel: all 1000 steps, 16 rows per block --------
__global__ __launch_bounds__(512)
void diffusion_main(const float* __restrict__ state, const float* __restrict__ x_init,
                    const float* __restrict__ w0, const float* __restrict__ b0,
                    const float* __restrict__ w1, const float* __restrict__ b1,
                    const float* __restrict__ w2, const float* __restrict__ b2,
                    const float* __restrict__ wf, const float* __restrict__ bf,
                    const float* __restrict__ tf_all, const float* __restrict__ coefs,
                    const uint32_t* __restrict__ keys, float* __restrict__ out) {
  // rows: r in [0,8) -> base+r ; r in [8,16) -> 2048+base+(r-8)
  __shared__ float s_in[16][CONC];   // [x(32) | tf(16) | state(128)]
  __shared__ float s_A[16][HID];
  __shared__ float s_B[16][HID];
  __shared__ float s_out[16][ADIM];

  const int tid = threadIdx.x;        // 0..511
  const int base = blockIdx.x * 8;
  const int r = tid >> 5;             // 0..15
  const int c = (tid & 31) * 4;       // 0..124

  for (int idx = tid; idx < 16 * ADIM; idx += 512) {
    int rr = idx >> 5, cc = idx & 31;
    int grow = (rr < 8) ? (base + rr) : (2048 + base + rr - 8);
    s_in[rr][cc] = x_init[grow * ADIM + cc];
  }
  for (int idx = tid; idx < 16 * SDIM; idx += 512) {
    int rr = idx >> 7, cc = idx & 127;
    int grow = (rr < 8) ? (base + rr) : (2048 + base + rr - 8);
    s_in[rr][ADIM + TDIM + cc] = state[grow * SDIM + cc];
  }
  __syncthreads();

  for (int t = T_STEPS - 1; t >= 0; --t) {
    if (tid < 256) {  // tf fill: 16 rows x 16 cols
      int rr = tid >> 4, cc = tid & 15;
      s_in[rr][ADIM + cc] = tf_all[t * TDIM + cc];
    }
    __syncthreads();
    dense48<CONC>(w0, b0, &s_in[0][0], CONC, &s_A[0][0], r, c);
    __syncthreads();
    dense48<HID>(w1, b1, &s_A[0][0], HID, &s_B[0][0], r, c);
    __syncthreads();
    dense48<HID>(w2, b2, &s_B[0][0], HID, &s_A[0][0], r, c);
    __syncthreads();
    {  // final 256->32: thread = (row r, dim d)
      int d = tid & 31;
      float acc = bf[d];
      const float* sa = &s_A[r][0];
      for (int k = 0; k < HID; k += 4) {
        float4 v = *reinterpret_cast<const float4*>(sa + k);
        acc = fmaf(v.x, wf[(k + 0) * ADIM + d], acc);
        acc = fmaf(v.y, wf[(k + 1) * ADIM + d], acc);
        acc = fmaf(v.z, wf[(k + 2) * ADIM + d], acc);
        acc = fmaf(v.w, wf[(k + 3) * ADIM + d], acc);
      }
      s_out[r][d] = acc;
    }
    __syncthreads();
    {  // posterior update + JAX partitionable-threefry noise; thread = (row r, dim d)
      int d = tid & 31;
      float sr  = coefs[0 * T_STEPS + t];
      float srm = coefs[1 * T_STEPS + t];
      float c1  = coefs[2 * T_STEPS + t];
      float c2  = coefs[3 * T_STEPS + t];
      float sig = (t != 0) ? coefs[4 * T_STEPS + t] : 0.0f;
      uint32_t k0 = keys[2 * t], k1 = keys[2 * t + 1];
      int grow = (r < 8) ? (base + r) : (2048 + base + r - 8);
      uint32_t jflat = (uint32_t)(grow * ADIM + d);
      float nz = bits_to_normal(random_bits32_partitionable(k0, k1, jflat));
      float xv = s_in[r][d];
      float eps = s_out[r][d];
      float x0v = fminf(fmaxf(sr * xv - srm * eps, -1.0f), 1.0f);
      s_in[r][d] = c1 * x0v + c2 * xv + sig * nz;
    }
    // next-iteration tf-fill writes cols [32,48) — disjoint from posterior's [0,32);
    // the tf-fill barrier orders posterior writes before dense0 reads.
  }
  __syncthreads();
  for (int idx = tid; idx < 16 * ADIM; idx += 512) {
    int rr = idx >> 5, cc = idx & 31;
    int grow = (rr < 8) ? (base + rr) : (2048 + base + rr - 8);
    out[grow * ADIM + cc] = fminf(fmaxf(s_in[rr][cc], -1.0f), 1.0f);
  }
}

// ---------------- launcher ----------------
extern "C" void kernel_launch(void* const* d_in, const int* in_sizes, int n_in,
                              void* d_out, int out_size, void* d_ws, size_t ws_size,
                              hipStream_t stream) {
  const float* state = (const float*)d_in[0];
  const float* x_init = (const float*)d_in[1];
  const float* w_t1 = (const float*)d_in[2];
  const float* b_t1 = (const float*)d_in[3];
  const float* w_t2 = (const float*)d_in[4];
  const float* b_t2 = (const float*)d_in[5];
  const float* w0 = (const float*)d_in[6];
  const float* b0 = (const float*)d_in[7];
  const float* w1 = (const float*)d_in[8];
  const float* b1 = (const float*)d_in[9];
  const float* w2 = (const float*)d_in[10];
  const float* b2 = (const float*)d_in[11];
  const float* wf = (const float*)d_in[12];
  const float* bf = (const float*)d_in[13];
  float* out = (float*)d_out;

  // workspace layout: tf_all[16000] | coefs[5000] | keys[2000 u32]  (= 92 KB)
  float* tf_all = (float*)d_ws;
  float* coefs = tf_all + T_STEPS * TDIM;
  uint32_t* keys = (uint32_t*)(coefs + 5 * T_STEPS);

  precompute_kernel<<<T_STEPS, 64, 0, stream>>>(w_t1, b_t1, w_t2, b_t2, tf_all, coefs, keys);
  diffusion_main<<<256, 512, 0, stream>>>(state, x_init, w0, b0, w1, b1, w2, b2,
                                          wf, bf, tf_all, coefs, keys, out);
}

// Round 6
// 23162.912 us; speedup vs baseline: 3.6009x; 3.6009x over previous
//
#include <hip/hip_runtime.h>
#include <stdint.h>

// ---------------- constants ----------------
#define T_STEPS 1000
#define BATCHN  4096
#define SDIM    128
#define ADIM    32
#define HID     256
#define TDIM    16
#define CONC    (ADIM + TDIM + SDIM)   // 176
#define KP0     200                    // padded K for layer0 (192 used, +8 stride pad)
#define KPH     264                    // padded K for hidden layers (256 used, +8)

typedef __attribute__((ext_vector_type(8))) short short8;   // 8 bf16 (4 VGPRs)
typedef __attribute__((ext_vector_type(4))) float f32x4;    // MFMA accumulator

// ---------------- bf16 helpers (RNE) ----------------
__device__ __forceinline__ unsigned short f2bf(float f) {
  uint32_t u = __float_as_uint(f);
  u = u + 0x7FFFu + ((u >> 16) & 1u);
  return (unsigned short)(u >> 16);
}
__device__ __forceinline__ float bf2f(unsigned short h) {
  return __uint_as_float(((uint32_t)h) << 16);
}

// ---------------- threefry2x32 (exact JAX semantics) ----------------
__device__ __forceinline__ uint32_t rotl32(uint32_t v, int d) {
  return (v << d) | (v >> (32 - d));
}
__device__ __forceinline__ void threefry2x32(uint32_t k0, uint32_t k1,
                                             uint32_t x0, uint32_t x1,
                                             uint32_t& o0, uint32_t& o1) {
  uint32_t ks0 = k0, ks1 = k1, ks2 = k0 ^ k1 ^ 0x1BD11BDAu;
  x0 += ks0; x1 += ks1;
#define TF_ROUND(r) { x0 += x1; x1 = rotl32(x1, (r)); x1 ^= x0; }
  TF_ROUND(13) TF_ROUND(15) TF_ROUND(26) TF_ROUND(6)
  x0 += ks1; x1 += ks2 + 1u;
  TF_ROUND(17) TF_ROUND(29) TF_ROUND(16) TF_ROUND(24)
  x0 += ks2; x1 += ks0 + 2u;
  TF_ROUND(13) TF_ROUND(15) TF_ROUND(26) TF_ROUND(6)
  x0 += ks0; x1 += ks1 + 3u;
  TF_ROUND(17) TF_ROUND(29) TF_ROUND(16) TF_ROUND(24)
  x0 += ks1; x1 += ks2 + 4u;
  TF_ROUND(13) TF_ROUND(15) TF_ROUND(26) TF_ROUND(6)
  x0 += ks2; x1 += ks0 + 5u;
#undef TF_ROUND
  o0 = x0; o1 = x1;
}
// JAX partitionable threefry random_bits (bit_width=32): XOR combine of both words.
__device__ __forceinline__ uint32_t random_bits32_partitionable(uint32_t k0, uint32_t k1,
                                                               uint32_t j) {
  uint32_t o0, o1;
  threefry2x32(k0, k1, 0u, j, o0, o1);
  return o0 ^ o1;
}

// ---------------- XLA ErfInv (f32 Giles polynomial) ----------------
__device__ __forceinline__ float erfinv_f32(float x) {
  float w = -log1pf(-(x * x));
  float p;
  if (w < 5.0f) {
    w = w - 2.5f;
    p = 2.81022636e-08f;
    p = fmaf(p, w, 3.43273939e-07f);
    p = fmaf(p, w, -3.5233877e-06f);
    p = fmaf(p, w, -4.39150654e-06f);
    p = fmaf(p, w, 0.00021858087f);
    p = fmaf(p, w, -0.00125372503f);
    p = fmaf(p, w, -0.00417768164f);
    p = fmaf(p, w, 0.246640727f);
    p = fmaf(p, w, 1.50140941f);
  } else {
    w = sqrtf(w) - 3.0f;
    p = -0.000200214257f;
    p = fmaf(p, w, 0.000100950558f);
    p = fmaf(p, w, 0.00134934322f);
    p = fmaf(p, w, -0.00367342844f);
    p = fmaf(p, w, 0.00573950773f);
    p = fmaf(p, w, -0.0076224613f);
    p = fmaf(p, w, 0.00943887047f);
    p = fmaf(p, w, 1.00167406f);
    p = fmaf(p, w, 2.83297682f);
  }
  return p * x;
}
__device__ __forceinline__ float bits_to_normal(uint32_t bits) {
  float f = __uint_as_float((bits >> 9) | 0x3F800000u) - 1.0f;   // [0,1)
  float u = f * 2.0f + (-0.99999994f);
  u = fmaxf(-0.99999994f, u);
  return 1.41421356237309515f * erfinv_f32(u);   // sqrt(2) as f32
}

// mish(x) = x * t/(t+2), t = e^x (e^x + 2); clamp arg (identical in f32 for x>=20)
__device__ __forceinline__ float mish_f(float x) {
  float e = expf(fminf(x, 20.0f));
  float t = fmaf(e, e, 2.0f * e);
  return x * (t / (t + 2.0f));
}

// ---------------- precompute: tf_all[1000][16], coefs[5][1000], keys[1000][2] --------
__global__ __launch_bounds__(64)
void precompute_kernel(const float* __restrict__ w_t1, const float* __restrict__ b_t1,
                       const float* __restrict__ w_t2, const float* __restrict__ b_t2,
                       float* __restrict__ tf_all, float* __restrict__ coefs,
                       uint32_t* __restrict__ keys) {
  const int i = blockIdx.x;
  const int j = threadIdx.x;
  const float tv = (float)i;
  __shared__ float hid[32];
  const float CF = (float)(-1.3157629102823120);  // -log(10000)/7
  if (j < 32) {
    float acc = b_t1[j];
#pragma unroll
    for (int k = 0; k < 16; ++k) {
      int kf = (k < 8) ? k : (k - 8);
      float fr = expf((float)kf * CF);
      float ang = tv * fr;
      float te = (k < 8) ? sinf(ang) : cosf(ang);
      acc = fmaf(te, w_t1[k * 32 + j], acc);
    }
    hid[j] = mish_f(acc);
  }
  __syncthreads();
  if (j < 16) {
    float acc = b_t2[j];
#pragma unroll
    for (int k2 = 0; k2 < 32; ++k2) acc = fmaf(hid[k2], w_t2[k2 * 16 + j], acc);
    tf_all[i * TDIM + j] = acc;
  }
  if (j == 0) {
    double t = (double)(i + 1);
    double ac  = exp(-0.1 * t / 1000.0 - 4.95 * t * t / 1.0e6);
    double acp = (i == 0) ? 1.0
        : exp(-0.1 * (t - 1.0) / 1000.0 - 4.95 * (t - 1.0) * (t - 1.0) / 1.0e6);
    double alpha = exp(-0.1 / 1000.0 - 4.95 * (2.0 * t - 1.0) / 1.0e6);
    double beta = 1.0 - alpha;
    double sr   = sqrt(1.0 / ac);
    double srm1 = sqrt(1.0 / ac - 1.0);
    double c1 = beta * sqrt(acp) / (1.0 - ac);
    double c2 = (1.0 - acp) * sqrt(alpha) / (1.0 - ac);
    double pv = beta * (1.0 - acp) / (1.0 - ac);
    double lv = log(fmax(pv, 1.0e-20));
    coefs[0 * T_STEPS + i] = (float)sr;
    coefs[1 * T_STEPS + i] = (float)srm1;
    coefs[2 * T_STEPS + i] = (float)c1;
    coefs[3 * T_STEPS + i] = (float)c2;
    float lvf = (float)lv;
    coefs[4 * T_STEPS + i] = expf(0.5f * lvf);
    uint32_t o0, o1;
    threefry2x32(0u, 1u, 0u, (uint32_t)i, o0, o1);
    keys[2 * i]     = o0;
    keys[2 * i + 1] = o1;
  }
}

// -------- prep: shuffle weights into MFMA B-fragment hi/lo layout -----------------
// frag layout per layer: idx = kt*NT + nt; ushort block of 1024 at frag + idx*1024:
//   [0..512)  = hi plane, lane l has j=0..7 at l*8+j  -> value W[kt*32+(l>>4)*8+j][nt*16+(l&15)]
//   [512..1024) = lo plane, same order
__global__ __launch_bounds__(64)
void prep_frags(const float* __restrict__ w0, const float* __restrict__ w1,
                const float* __restrict__ w2, const float* __restrict__ wf,
                unsigned short* __restrict__ f0, unsigned short* __restrict__ f1,
                unsigned short* __restrict__ f2, unsigned short* __restrict__ ff) {
  const int bid = blockIdx.x;   // 0..367
  const int l = threadIdx.x;    // 0..63
  const float* W; unsigned short* F; int NT, Kmax, N, idx;
  if (bid < 96)       { W = w0; F = f0; NT = 16; Kmax = CONC; N = 256; idx = bid; }
  else if (bid < 224) { W = w1; F = f1; NT = 16; Kmax = 256;  N = 256; idx = bid - 96; }
  else if (bid < 352) { W = w2; F = f2; NT = 16; Kmax = 256;  N = 256; idx = bid - 224; }
  else                { W = wf; F = ff; NT = 2;  Kmax = 256;  N = 32;  idx = bid - 352; }
  const int kt = idx / NT, nt = idx % NT;
  const int n = nt * 16 + (l & 15);
  const int kbase = kt * 32 + (l >> 4) * 8;
  unsigned short* dst = F + idx * 1024 + l * 8;
#pragma unroll
  for (int j = 0; j < 8; ++j) {
    int k = kbase + j;
    float v = (k < Kmax) ? W[k * N + n] : 0.0f;
    unsigned short h = f2bf(v);
    dst[j]       = h;
    dst[512 + j] = f2bf(v - bf2f(h));
  }
}

// ---------------- persistent main kernel: split-bf16 MFMA, 16 rows/block ----------
__global__ __launch_bounds__(512)
void diffusion_main(const float* __restrict__ state, const float* __restrict__ x_init,
                    const float* __restrict__ b0, const float* __restrict__ b1,
                    const float* __restrict__ b2, const float* __restrict__ bf,
                    const unsigned short* __restrict__ f0, const unsigned short* __restrict__ f1,
                    const unsigned short* __restrict__ f2, const unsigned short* __restrict__ ff,
                    const float* __restrict__ tf_all, const float* __restrict__ coefs,
                    const uint32_t* __restrict__ keys, float* __restrict__ out) {
  __shared__ __align__(16) unsigned short a0h[16][KP0], a0l[16][KP0];
  __shared__ __align__(16) unsigned short aAh[16][KPH], aAl[16][KPH];
  __shared__ __align__(16) unsigned short aBh[16][KPH], aBl[16][KPH];
  __shared__ float s_x[16][ADIM];
  __shared__ float s_eps[16][ADIM];

  const int tid = threadIdx.x;          // 0..511
  const int base = blockIdx.x * 8;
  const int l = tid & 63;               // lane
  const int w = tid >> 6;               // wave 0..7
  const int lrow = l & 15;              // MFMA row / col-index within tile
  const int quad = l >> 4;              // 0..3
  const int nt0 = 2 * w, nt1 = 2 * w + 1;

  // ---- init: x, state (hi/lo), zero pad ----
  for (int idx = tid; idx < 16 * ADIM; idx += 512) {
    int r = idx >> 5, d = idx & 31;
    int grow = (r < 8) ? (base + r) : (2048 + base + r - 8);
    float v = x_init[grow * ADIM + d];
    s_x[r][d] = v;
    unsigned short h = f2bf(v);
    a0h[r][d] = h; a0l[r][d] = f2bf(v - bf2f(h));
  }
  for (int idx = tid; idx < 16 * SDIM; idx += 512) {
    int r = idx >> 7, c = idx & 127;
    int grow = (r < 8) ? (base + r) : (2048 + base + r - 8);
    float v = state[grow * SDIM + c];
    unsigned short h = f2bf(v);
    a0h[r][ADIM + TDIM + c] = h; a0l[r][ADIM + TDIM + c] = f2bf(v - bf2f(h));
  }
  for (int idx = tid; idx < 16 * (KP0 - CONC); idx += 512) {
    int r = idx / (KP0 - CONC), c = CONC + idx % (KP0 - CONC);
    a0h[r][c] = 0; a0l[r][c] = 0;
  }

  // ---- per-lane constant bias preload ----
  const float b0A = b0[nt0 * 16 + lrow], b0B = b0[nt1 * 16 + lrow];
  const float b1A = b1[nt0 * 16 + lrow], b1B = b1[nt1 * 16 + lrow];
  const float b2A = b2[nt0 * 16 + lrow], b2B = b2[nt1 * 16 + lrow];
  const float bfv = (w < 2) ? bf[w * 16 + lrow] : 0.0f;
  __syncthreads();

  // ---- dense layer via split-bf16 MFMA (wave handles col-tiles nt0, nt1) ----
  auto dense_mfma = [&](const unsigned short* srcH, const unsigned short* srcL, int kp,
                        int nkt, const unsigned short* frag, float bA, float bB,
                        unsigned short* dstH, unsigned short* dstL, int dkp) {
    f32x4 acc0 = {0.f, 0.f, 0.f, 0.f}, acc1 = {0.f, 0.f, 0.f, 0.f};
    const unsigned short* aH = srcH + lrow * kp + quad * 8;
    const unsigned short* aL = srcL + lrow * kp + quad * 8;
    for (int kt = 0; kt < nkt; ++kt) {
      short8 ah = *reinterpret_cast<const short8*>(aH + kt * 32);
      short8 al = *reinterpret_cast<const short8*>(aL + kt * 32);
      const unsigned short* fb0 = frag + (kt * 16 + nt0) * 1024 + l * 8;
      const unsigned short* fb1 = frag + (kt * 16 + nt1) * 1024 + l * 8;
      short8 bh0 = *reinterpret_cast<const short8*>(fb0);
      short8 bl0 = *reinterpret_cast<const short8*>(fb0 + 512);
      short8 bh1 = *reinterpret_cast<const short8*>(fb1);
      short8 bl1 = *reinterpret_cast<const short8*>(fb1 + 512);
      acc0 = __builtin_amdgcn_mfma_f32_16x16x32_bf16(ah, bh0, acc0, 0, 0, 0);
      acc1 = __builtin_amdgcn_mfma_f32_16x16x32_bf16(ah, bh1, acc1, 0, 0, 0);
      acc0 = __builtin_amdgcn_mfma_f32_16x16x32_bf16(al, bh0, acc0, 0, 0, 0);
      acc1 = __builtin_amdgcn_mfma_f32_16x16x32_bf16(al, bh1, acc1, 0, 0, 0);
      acc0 = __builtin_amdgcn_mfma_f32_16x16x32_bf16(ah, bl0, acc0, 0, 0, 0);
      acc1 = __builtin_amdgcn_mfma_f32_16x16x32_bf16(ah, bl1, acc1, 0, 0, 0);
    }
    // epilogue: C/D layout col=lane&15, row=quad*4+reg
#pragma unroll
    for (int reg = 0; reg < 4; ++reg) {
      int orow = quad * 4 + reg;
      float v0 = mish_f(acc0[reg] + bA);
      float v1 = mish_f(acc1[reg] + bB);
      unsigned short h0 = f2bf(v0), h1 = f2bf(v1);
      dstH[orow * dkp + nt0 * 16 + lrow] = h0;
      dstL[orow * dkp + nt0 * 16 + lrow] = f2bf(v0 - bf2f(h0));
      dstH[orow * dkp + nt1 * 16 + lrow] = h1;
      dstL[orow * dkp + nt1 * 16 + lrow] = f2bf(v1 - bf2f(h1));
    }
  };

  for (int t = T_STEPS - 1; t >= 0; --t) {
    if (tid < 256) {  // tf fill: 16 rows x 16 cols (hi/lo)
      int r = tid >> 4, c = tid & 15;
      float v = tf_all[t * TDIM + c];
      unsigned short h = f2bf(v);
      a0h[r][ADIM + c] = h; a0l[r][ADIM + c] = f2bf(v - bf2f(h));
    }
    __syncthreads();
    dense_mfma(&a0h[0][0], &a0l[0][0], KP0, 6, f0, b0A, b0B, &aAh[0][0], &aAl[0][0], KPH);
    __syncthreads();
    dense_mfma(&aAh[0][0], &aAl[0][0], KPH, 8, f1, b1A, b1B, &aBh[0][0], &aBl[0][0], KPH);
    __syncthreads();
    dense_mfma(&aBh[0][0], &aBl[0][0], KPH, 8, f2, b2A, b2B, &aAh[0][0], &aAl[0][0], KPH);
    __syncthreads();
    if (w < 2) {  // final 256->32: waves 0,1, one col-tile each
      f32x4 acc = {0.f, 0.f, 0.f, 0.f};
      const unsigned short* aH = &aAh[0][0] + lrow * KPH + quad * 8;
      const unsigned short* aL = &aAl[0][0] + lrow * KPH + quad * 8;
      for (int kt = 0; kt < 8; ++kt) {
        short8 ah = *reinterpret_cast<const short8*>(aH + kt * 32);
        short8 al = *reinterpret_cast<const short8*>(aL + kt * 32);
        const unsigned short* fb = ff + (kt * 2 + w) * 1024 + l * 8;
        short8 bh = *reinterpret_cast<const short8*>(fb);
        short8 bl = *reinterpret_cast<const short8*>(fb + 512);
        acc = __builtin_amdgcn_mfma_f32_16x16x32_bf16(ah, bh, acc, 0, 0, 0);
        acc = __builtin_amdgcn_mfma_f32_16x16x32_bf16(al, bh, acc, 0, 0, 0);
        acc = __builtin_amdgcn_mfma_f32_16x16x32_bf16(ah, bl, acc, 0, 0, 0);
      }
#pragma unroll
      for (int reg = 0; reg < 4; ++reg)
        s_eps[quad * 4 + reg][w * 16 + lrow] = acc[reg] + bfv;
    }
    __syncthreads();
    {  // posterior update + JAX noise; thread = (row r, dim d); also refresh a0 x-cols
      int d = tid & 31;
      int r = tid >> 5;
      float sr  = coefs[0 * T_STEPS + t];
      float srm = coefs[1 * T_STEPS + t];
      float c1  = coefs[2 * T_STEPS + t];
      float c2  = coefs[3 * T_STEPS + t];
      float sig = (t != 0) ? coefs[4 * T_STEPS + t] : 0.0f;
      uint32_t k0 = keys[2 * t], k1 = keys[2 * t + 1];
      int grow = (r < 8) ? (base + r) : (2048 + base + r - 8);
      uint32_t jflat = (uint32_t)(grow * ADIM + d);
      float nz = bits_to_normal(random_bits32_partitionable(k0, k1, jflat));
      float xv = s_x[r][d];
      float eps = s_eps[r][d];
      float x0v = fminf(fmaxf(sr * xv - srm * eps, -1.0f), 1.0f);
      float xn = c1 * x0v + c2 * xv + sig * nz;
      s_x[r][d] = xn;
      unsigned short h = f2bf(xn);
      a0h[r][d] = h; a0l[r][d] = f2bf(xn - bf2f(h));
    }
    // loop-top tf fill writes a0 cols [32,48) (disjoint from posterior's [0,32));
    // its barrier orders everything before the next L0 MFMA reads.
  }
  __syncthreads();
  for (int idx = tid; idx < 16 * ADIM; idx += 512) {
    int r = idx >> 5, c = idx & 31;
    int grow = (r < 8) ? (base + r) : (2048 + base + r - 8);
    out[grow * ADIM + c] = fminf(fmaxf(s_x[r][c], -1.0f), 1.0f);
  }
}

// ---------------- launcher ----------------
extern "C" void kernel_launch(void* const* d_in, const int* in_sizes, int n_in,
                              void* d_out, int out_size, void* d_ws, size_t ws_size,
                              hipStream_t stream) {
  const float* state = (const float*)d_in[0];
  const float* x_init = (const float*)d_in[1];
  const float* w_t1 = (const float*)d_in[2];
  const float* b_t1 = (const float*)d_in[3];
  const float* w_t2 = (const float*)d_in[4];
  const float* b_t2 = (const float*)d_in[5];
  const float* w0 = (const float*)d_in[6];
  const float* b0 = (const float*)d_in[7];
  const float* w1 = (const float*)d_in[8];
  const float* b1 = (const float*)d_in[9];
  const float* w2 = (const float*)d_in[10];
  const float* b2 = (const float*)d_in[11];
  const float* wf = (const float*)d_in[12];
  const float* bf = (const float*)d_in[13];
  float* out = (float*)d_out;

  // ws layout: tf_all[16000] f32 | coefs[5000] f32 | keys[2000] u32 (92160 B, 16-aligned)
  //            | f0[98304] ush | f1[131072] | f2[131072] | ff[16384]   (~830 KB total)
  float* tf_all = (float*)d_ws;
  float* coefs = tf_all + T_STEPS * TDIM;
  uint32_t* keys = (uint32_t*)(coefs + 5 * T_STEPS);
  unsigned short* f0 = (unsigned short*)(keys + 2 * T_STEPS);
  unsigned short* f1 = f0 + 96 * 1024;
  unsigned short* f2 = f1 + 128 * 1024;
  unsigned short* ff = f2 + 128 * 1024;

  precompute_kernel<<<T_STEPS, 64, 0, stream>>>(w_t1, b_t1, w_t2, b_t2, tf_all, coefs, keys);
  prep_frags<<<368, 64, 0, stream>>>(w0, w1, w2, wf, f0, f1, f2, ff);
  diffusion_main<<<256, 512, 0, stream>>>(state, x_init, b0, b1, b2, bf,
                                          f0, f1, f2, ff, tf_all, coefs, keys, out);
}